// Round 7
// baseline (227.433 us; speedup 1.0000x reference)
//
#include <hip/hip_runtime.h>
#include <math.h>

// ---------------------------------------------------------------------------
// PreLossSampler (N=1024):
//   out = [reg_valid | labels | max_overlaps | gt_assignment]  (4096 float32)
//
// 4-kernel pipeline:
//   prep3  : 16x64. reg_valid/labels, circles, sup zero-init, RANK-based
//            stable argsort(-labels) (each lane counts its key's rank against
//            all 1024 keys -> exact stable ranks, no barriers), scatter
//            order/sbox/circ_s.
//   fusedA : 128x64, block owns 8 strided sorted-gt rows. Circle-reject scan
//            compacts survivors into a 256-entry LDS ring; drains dense
//            64-lane clip batches. Suppression bits -> LDS (32-bit atomicOr),
//            written to sup once per block. No worklists, no global atomics.
//   nms_seq5: greedy NMS, one wave (validated round 6).
//   fusedB : 128x64, block owns 8 strided pred rows. sampled[j]+circle scan,
//            same ring/dense-eval; per-row (iou,first-idx) packed u64 LDS
//            atomicMax; writes out[2],out[3] directly (fin eliminated).
//
// Exactness: circle-rejected pairs have polygon area exactly 0 in the
// reference; non-sampled gt are skipped (iou 0 never beats pack(0,j=0) init);
// rank sort reproduces stable argsort; clip is the round-6-validated
// scratch-free version (all arrays <= 96 B). Validated absmax 0.0.
// ---------------------------------------------------------------------------

#define NB 1024
#define FB 128  // fused-kernel blocks; each owns 8 strided rows

typedef unsigned long long u64;

__device__ __forceinline__ bool pt_in_box(float px, float py,
        float bx, float by, float bdx, float bdy, float cs, float sn) {
    float dx = px - bx, dy = py - by;
    float lx = dx * cs + dy * sn;
    float ly = dy * cs - dx * sn;
    return (fabsf(lx) <= bdx * 0.5f + 1e-5f) && (fabsf(ly) <= bdy * 0.5f + 1e-5f);
}

// total-order sortable bits of a float (with -0 canonicalized via +0.0f)
__device__ __forceinline__ unsigned sortbits(float f) {
    unsigned u = __float_as_uint(f + 0.0f);
    return (u & 0x80000000u) ? ~u : (u | 0x80000000u);
}

// Rotated-rectangle intersection area; reference-exact op order; all arrays
// <= 96 B and statically indexed (register-resident, zero scratch).
// Validated absmax 0.0 (round 6).
__device__ float rect_inter_area(
        float ax, float ay, float adx, float ady, float ar,
        float bx, float by, float bdx, float bdy, float br) {
    float dcx = ax - bx, dcy = ay - by;
    float ra = 0.5f * sqrtf(adx * adx + ady * ady);
    float rb = 0.5f * sqrtf(bdx * bdx + bdy * bdy);
    float lim = ra + rb + 1e-3f;
    if (dcx * dcx + dcy * dcy > lim * lim) return 0.0f;

    float csa = cosf(ar), sna = sinf(ar);
    float csb = cosf(br), snb = sinf(br);
    float cax[4], cay[4], cbx[4], cby[4];
    const float SX[4] = {0.5f, 0.5f, -0.5f, -0.5f};
    const float SY[4] = {0.5f, -0.5f, -0.5f, 0.5f};
#pragma unroll
    for (int i = 0; i < 4; ++i) {
        float lx = SX[i] * adx, ly = SY[i] * ady;
        cax[i] = lx * csa - ly * sna + ax;
        cay[i] = lx * sna + ly * csa + ay;
        float mx = SX[i] * bdx, my = SY[i] * bdy;
        cbx[i] = mx * csb - my * snb + bx;
        cby[i] = mx * snb + my * csb + by;
    }

    unsigned vmask = 0u;
    float sx = 0.0f, sy = 0.0f;
#pragma unroll
    for (int i = 0; i < 4; ++i) {
        bool v = pt_in_box(cax[i], cay[i], bx, by, bdx, bdy, csb, snb);
        vmask |= v ? (1u << i) : 0u;
        sx += v ? cax[i] : 0.0f;
        sy += v ? cay[i] : 0.0f;
    }
#pragma unroll
    for (int i = 0; i < 4; ++i) {
        bool v = pt_in_box(cbx[i], cby[i], ax, ay, adx, ady, csa, sna);
        vmask |= v ? (1u << (4 + i)) : 0u;
        sx += v ? cbx[i] : 0.0f;
        sy += v ? cby[i] : 0.0f;
    }
#pragma unroll
    for (int i = 0; i < 4; ++i) {
        float a0x = cax[i], a0y = cay[i];
        float d1x = cax[(i + 1) & 3] - a0x, d1y = cay[(i + 1) & 3] - a0y;
#pragma unroll
        for (int j = 0; j < 4; ++j) {
            int s = 8 + i * 4 + j;
            float b0x = cbx[j], b0y = cby[j];
            float d2x = cbx[(j + 1) & 3] - b0x, d2y = cby[(j + 1) & 3] - b0y;
            float r0x = b0x - a0x, r0y = b0y - a0y;
            float den = d1x * d2y - d1y * d2x;
            bool nz = fabsf(den) > 1e-8f;
            float sden = nz ? den : 1.0f;
            float t = (r0x * d2y - r0y * d2x) / sden;
            float u = (r0x * d1y - r0y * d1x) / sden;
            bool ok = nz && t >= 0.0f && t <= 1.0f && u >= 0.0f && u <= 1.0f;
            float ipx = a0x + t * d1x;
            float ipy = a0y + t * d1y;
            vmask |= ok ? (1u << s) : 0u;
            sx += ok ? ipx : 0.0f;
            sy += ok ? ipy : 0.0f;
        }
    }
    int kc = __popc(vmask);
    if (kc < 3) return 0.0f;
    float ctrx = sx / (float)kc, ctry = sy / (float)kc;

    float cx24[24], cy24[24];
    unsigned h[24];
#pragma unroll
    for (int i = 0; i < 4; ++i) {
        {
            bool v = (vmask >> i) & 1u;
            float cx = v ? cax[i] - ctrx : 0.0f;
            float cy = v ? cay[i] - ctry : 0.0f;
            cx24[i] = cx; cy24[i] = cy;
            h[i] = sortbits(v ? atan2f(cy, cx) : 1e9f);
        }
        {
            bool v = (vmask >> (4 + i)) & 1u;
            float cx = v ? cbx[i] - ctrx : 0.0f;
            float cy = v ? cby[i] - ctry : 0.0f;
            cx24[4 + i] = cx; cy24[4 + i] = cy;
            h[4 + i] = sortbits(v ? atan2f(cy, cx) : 1e9f);
        }
    }
#pragma unroll
    for (int i = 0; i < 4; ++i) {
        float a0x = cax[i], a0y = cay[i];
        float d1x = cax[(i + 1) & 3] - a0x, d1y = cay[(i + 1) & 3] - a0y;
#pragma unroll
        for (int j = 0; j < 4; ++j) {
            int s = 8 + i * 4 + j;
            float b0x = cbx[j], b0y = cby[j];
            float d2x = cbx[(j + 1) & 3] - b0x, d2y = cby[(j + 1) & 3] - b0y;
            float r0x = b0x - a0x, r0y = b0y - a0y;
            float den = d1x * d2y - d1y * d2x;
            bool nz = fabsf(den) > 1e-8f;
            float sden = nz ? den : 1.0f;
            float t = (r0x * d2y - r0y * d2x) / sden;
            bool v = (vmask >> s) & 1u;
            float ipx = a0x + t * d1x;
            float ipy = a0y + t * d1y;
            float cx = v ? ipx - ctrx : 0.0f;
            float cy = v ? ipy - ctry : 0.0f;
            cx24[s] = cx; cy24[s] = cy;
            h[s] = sortbits(v ? atan2f(cy, cx) : 1e9f);
        }
    }

    int rk[24];
#pragma unroll
    for (int s = 0; s < 24; ++s) rk[s] = 0;
#pragma unroll
    for (int s = 0; s < 24; ++s) {
#pragma unroll
        for (int t = s + 1; t < 24; ++t) {
            bool a = h[s] <= h[t];
            rk[t] += a ? 1 : 0;
            rk[s] += a ? 0 : 1;
        }
    }

    float acc = 0.0f;
    float fx = 0.0f, fy = 0.0f, lx = 0.0f, ly = 0.0f;
    float pxp = 0.0f, pyp = 0.0f;
#pragma unroll
    for (int p = 0; p < 24; ++p) {
        float X = 0.0f, Y = 0.0f;
#pragma unroll
        for (int s = 0; s < 24; ++s) {
            bool m = (rk[s] == p);
            X = m ? cx24[s] : X;
            Y = m ? cy24[s] : Y;
        }
        if (p == 0) {
            fx = X; fy = Y;
        } else {
            float cr = pxp * Y - pyp * X;
            acc += (p < kc) ? cr : 0.0f;
        }
        bool e = (p == kc - 1);
        lx = e ? X : lx;
        ly = e ? Y : ly;
        pxp = X; pyp = Y;
    }
    acc += lx * fy - ly * fx;
    return 0.5f * fabsf(acc);
}

// ---------------------------------------------------------------------------
// prep3: 16 blocks x 64. Elementwise outputs, circles, sup zero, rank sort.
// rank[s] = #{t: k_t > k_s} + #{t < s: k_t == k_s}  (== stable argsort pos)
// ---------------------------------------------------------------------------
__global__ __launch_bounds__(64) void prep3_kernel(
        const float* __restrict__ labels, const float* __restrict__ cls,
        const float* __restrict__ gt, const float* __restrict__ pred,
        float* __restrict__ out, int* __restrict__ order,
        float* __restrict__ sbox, float4* __restrict__ circ_s,
        float4* __restrict__ circ_g, float4* __restrict__ circ_p,
        u64* __restrict__ sup) {
    int lane = threadIdx.x;
    int s = blockIdx.x * 64 + lane;
    float lab = labels[s];
    float sig = 1.0f / (1.0f + expf(-cls[s]));
    out[s] = (sig > 0.55f && lab > 0.55f) ? 1.0f : 0.0f;
    out[NB + s] = lab;

#pragma unroll
    for (int rep = 0; rep < 16; ++rep) sup[rep * 1024 + s] = 0ULL;

    float gx = gt[s * 8 + 0], gy = gt[s * 8 + 1];
    float gdx = gt[s * 8 + 3], gdy = gt[s * 8 + 4];
    float4 cg = make_float4(gx, gy, 0.5f * sqrtf(gdx * gdx + gdy * gdy), 0.0f);
    circ_g[s] = cg;
    float ppx = pred[s * 7 + 0], ppy = pred[s * 7 + 1];
    float pdx = pred[s * 7 + 3], pdy = pred[s * 7 + 4];
    circ_p[s] = make_float4(ppx, ppy, 0.5f * sqrtf(pdx * pdx + pdy * pdy), 0.0f);

    int rank = 0;
    const float4* lab4 = (const float4*)labels;
#pragma unroll 8
    for (int t4 = 0; t4 < 256; ++t4) {
        float4 kv = lab4[t4];
        int t = t4 * 4;
        rank += ((kv.x > lab) || (kv.x == lab && (t + 0) < s)) ? 1 : 0;
        rank += ((kv.y > lab) || (kv.y == lab && (t + 1) < s)) ? 1 : 0;
        rank += ((kv.z > lab) || (kv.z == lab && (t + 2) < s)) ? 1 : 0;
        rank += ((kv.w > lab) || (kv.w == lab && (t + 3) < s)) ? 1 : 0;
    }
    order[rank] = s;
#pragma unroll
    for (int c = 0; c < 7; ++c) sbox[rank * 8 + c] = gt[s * 8 + c];
    sbox[rank * 8 + 7] = 0.0f;
    circ_s[rank] = cg;
}

// ---------------------------------------------------------------------------
// fusedA: gt x gt (sorted space, j > i) -> suppression bitmask.
// Block b owns rows i = b + r*FB (r in 0..8). Circle-survivors compact into a
// 256-entry LDS ring; dense 64-lane clip batch drains when >= 64 pending.
// Ring occupancy never exceeds 127 (<=63 leftover + <=64 appended) < 256.
// ---------------------------------------------------------------------------
__device__ __forceinline__ void evalA_pair(unsigned p, int b,
        const float* __restrict__ sbox, unsigned* sup32) {
    int i = (p >> 10) & 1023, j = p & 1023;
    const float* A = &sbox[i * 8];
    const float* B = &sbox[j * 8];
    float inter = rect_inter_area(A[0], A[1], A[3], A[4], A[6],
                                  B[0], B[1], B[3], B[4], B[6]);
    float iou = inter / fmaxf(A[3] * A[4] + B[3] * B[4] - inter, 1e-8f);
    if (iou > 0.1f) {
        int r = (i - b) >> 7;
        atomicOr(&sup32[r * 32 + (j >> 5)], 1u << (j & 31));
    }
}

__global__ __launch_bounds__(64, 1) void fusedA_kernel(
        const float* __restrict__ sbox, const float4* __restrict__ circ_s,
        u64* __restrict__ sup) {
    __shared__ unsigned ring[256];
    __shared__ unsigned sup32[8 * 32];
    int lane = threadIdx.x;
    int b = blockIdx.x;
    for (int t = lane; t < 256; t += 64) sup32[t] = 0u;
    __syncthreads();

    unsigned head = 0, tail = 0;
#pragma unroll
    for (int r = 0; r < 8; ++r) {
        int i = b + r * FB;
        float4 A = circ_s[i];
        int j0 = ((i + 1) >> 6) << 6;  // first 64-aligned chunk containing j>i
        for (int jb = j0; jb < 1024; jb += 64) {
            int j = jb + lane;
            bool q = j > i;
            if (q) {
                float4 B = circ_s[j];
                float dx = A.x - B.x, dy = A.y - B.y;
                float lim = A.z + B.z + 1e-3f;
                q = (dx * dx + dy * dy) <= lim * lim;
            }
            u64 m = __ballot(q ? 1 : 0);
            if (q) {
                unsigned pos =
                    tail + (unsigned)__popcll(m & ((1ULL << lane) - 1ULL));
                ring[pos & 255u] = (unsigned)((i << 10) | j);
            }
            tail += (unsigned)__popcll(m);
            if (tail - head >= 64u) {  // wave-uniform
                __syncthreads();
                unsigned pp = ring[(head + lane) & 255u];
                evalA_pair(pp, b, sbox, sup32);
                head += 64u;
            }
        }
    }
    if (tail > head) {
        __syncthreads();
        unsigned rem = tail - head;
        if ((unsigned)lane < rem)
            evalA_pair(ring[(head + lane) & 255u], b, sbox, sup32);
    }
    __syncthreads();
    for (int t = lane; t < 128; t += 64) {
        int r = t >> 4, w = t & 15;
        int i = b + r * FB;
        sup[i * 16 + w] = (u64)sup32[r * 32 + 2 * w] |
                          ((u64)sup32[r * 32 + 2 * w + 1] << 32);
    }
}

// ---------------------------------------------------------------------------
// nms_seq5: greedy NMS, one wave (validated round 6).
// ---------------------------------------------------------------------------
__global__ __launch_bounds__(64, 1) void nms_seq5_kernel(
        const u64* __restrict__ sup, const int* __restrict__ order,
        int* __restrict__ sampled) {
    __shared__ u64 bc[64];
    int lane = threadIdx.x;
    u64 kw[16];
    u64 acc[16];
    u64 row[16];
#pragma unroll
    for (int t = 0; t < 16; ++t) acc[t] = 0ULL;
#pragma unroll
    for (int t = 0; t < 16; ++t)
        row[t] = sup[(size_t)lane * 16 + t];

#pragma unroll
    for (int W = 0; W < 16; ++W) {
        u64 v = acc[W];
#pragma unroll
        for (int off = 32; off > 0; off >>= 1) v |= __shfl_xor(v, off, 64);
        u64 kwW = ~v;

        bc[lane] = row[W];
        __syncthreads();

        u64 rowN[16];
#pragma unroll
        for (int t = 0; t < 16; ++t) rowN[t] = 0ULL;
        if (W < 15) {
#pragma unroll
            for (int t = 0; t < 16; ++t)
                if (t >= W + 1)
                    rowN[t] = sup[(size_t)((W + 1) * 64 + lane) * 16 + t];
        }

#pragma unroll
        for (int bb = 0; bb < 64; ++bb) {
            bool kb = (kwW >> bb) & 1ULL;
            kwW &= kb ? ~bc[bb] : ~0ULL;
        }
        kw[W] = kwW;

        bool me = (kwW >> lane) & 1ULL;
#pragma unroll
        for (int t = W + 1; t < 16; ++t) acc[t] |= me ? row[t] : 0ULL;

        __syncthreads();
#pragma unroll
        for (int t = 0; t < 16; ++t) row[t] = rowN[t];
    }

#pragma unroll
    for (int t = 0; t < 16; ++t) {
        int idx = t * 64 + lane;
        int bit = (int)((kw[t] >> lane) & 1ULL);
        sampled[order[idx]] = bit;
    }
}

// ---------------------------------------------------------------------------
// fusedB: pred x gt (sampled-filtered) -> per-row max IoU3D + argmax.
// Same ring structure; per-row packed (iou, 1023-j) u64 LDS atomicMax;
// writes out[2],out[3] directly.
// ---------------------------------------------------------------------------
__device__ __forceinline__ void evalB_pair(unsigned p, int b,
        const float* __restrict__ pred, const float* __restrict__ gt,
        u64* rm) {
    int i = (p >> 10) & 1023, j = p & 1023;
    float Ax = pred[i * 7 + 0], Ay = pred[i * 7 + 1], Az = pred[i * 7 + 2];
    float Adx = pred[i * 7 + 3], Ady = pred[i * 7 + 4], Adz = pred[i * 7 + 5];
    float Ar = pred[i * 7 + 6];
    float Bx = gt[j * 8 + 0], By = gt[j * 8 + 1], Bz = gt[j * 8 + 2];
    float Bdx = gt[j * 8 + 3], Bdy = gt[j * 8 + 4], Bdz = gt[j * 8 + 5];
    float Br = gt[j * 8 + 6];
    float inter = rect_inter_area(Ax, Ay, Adx, Ady, Ar, Bx, By, Bdx, Bdy, Br);
    float amax = Az + Adz * 0.5f, amin = Az - Adz * 0.5f;
    float bmax = Bz + Bdz * 0.5f, bmin = Bz - Bdz * 0.5f;
    float oh = fmaxf(fminf(amax, bmax) - fmaxf(amin, bmin), 0.0f);
    float inter3d = inter * oh;
    float va = Adx * Ady * Adz, vb = Bdx * Bdy * Bdz;
    float iou = inter3d / fmaxf(va + vb - inter3d, 1e-8f);
    u64 pk = (((u64)__float_as_uint(iou)) << 32) | (u64)(1023 - j);
    int r = (i - b) >> 7;
    atomicMax(&rm[r], pk);
}

__global__ __launch_bounds__(64, 1) void fusedB_kernel(
        const float* __restrict__ pred, const float* __restrict__ gt,
        const int* __restrict__ sampled, const float4* __restrict__ circ_p,
        const float4* __restrict__ circ_g, float* __restrict__ out) {
    __shared__ unsigned ring[256];
    __shared__ u64 rm[8];
    int lane = threadIdx.x;
    int b = blockIdx.x;
    if (lane < 8) rm[lane] = 1023ULL;  // pack(iou=0.0f, j=0)
    __syncthreads();

    unsigned head = 0, tail = 0;
#pragma unroll
    for (int r = 0; r < 8; ++r) {
        int i = b + r * FB;
        float4 A = circ_p[i];
        for (int jb = 0; jb < 1024; jb += 64) {
            int j = jb + lane;
            bool q = sampled[j] != 0;
            if (q) {
                float4 B = circ_g[j];
                float dx = A.x - B.x, dy = A.y - B.y;
                float lim = A.z + B.z + 1e-3f;
                q = (dx * dx + dy * dy) <= lim * lim;
            }
            u64 m = __ballot(q ? 1 : 0);
            if (q) {
                unsigned pos =
                    tail + (unsigned)__popcll(m & ((1ULL << lane) - 1ULL));
                ring[pos & 255u] = (unsigned)((i << 10) | j);
            }
            tail += (unsigned)__popcll(m);
            if (tail - head >= 64u) {
                __syncthreads();
                unsigned pp = ring[(head + lane) & 255u];
                evalB_pair(pp, b, pred, gt, rm);
                head += 64u;
            }
        }
    }
    if (tail > head) {
        __syncthreads();
        unsigned rem = tail - head;
        if ((unsigned)lane < rem)
            evalB_pair(ring[(head + lane) & 255u], b, pred, gt, rm);
    }
    __syncthreads();
    if (lane < 8) {
        int i = b + lane * FB;
        u64 v = rm[lane];
        float fv = __uint_as_float((unsigned)(v >> 32));
        int j = 1023 - (int)(v & 0xFFFFFFFFULL);
        float mo = (fv > 0.75f) ? 1.0f : ((fv < 0.25f) ? 0.0f : fv);
        out[2 * NB + i] = mo;
        out[3 * NB + i] = (float)j;
    }
}

// ---------------------------------------------------------------------------
// Fallback dense kernels (only if ws too small — never taken in practice).
// ---------------------------------------------------------------------------
__global__ __launch_bounds__(1024) void prep_kernel(
        const float* __restrict__ labels, const float* __restrict__ cls,
        const float* __restrict__ gt, float* __restrict__ out,
        int* __restrict__ order, float* __restrict__ sbox,
        u64* __restrict__ rowmax) {
    int tid = threadIdx.x;
    float lab = labels[tid];
    float sig = 1.0f / (1.0f + expf(-cls[tid]));
    out[tid] = (sig > 0.55f && lab > 0.55f) ? 1.0f : 0.0f;
    out[NB + tid] = lab;
    rowmax[tid] = 1023ULL;
    __shared__ float key[NB];
    __shared__ int idx[NB];
    key[tid] = lab;
    idx[tid] = tid;
    __syncthreads();
    for (int k = 2; k <= NB; k <<= 1) {
        for (int j = k >> 1; j > 0; j >>= 1) {
            int p = tid ^ j;
            if (p > tid) {
                float k1 = key[tid], k2 = key[p];
                int i1 = idx[tid], i2 = idx[p];
                bool lessPT = (k2 > k1) || (k2 == k1 && i2 < i1);
                bool asc = (tid & k) == 0;
                bool doswap = asc ? lessPT : !lessPT;
                if (doswap) {
                    key[tid] = k2; key[p] = k1;
                    idx[tid] = i2; idx[p] = i1;
                }
            }
            __syncthreads();
        }
    }
    int o = idx[tid];
    order[tid] = o;
#pragma unroll
    for (int c = 0; c < 7; ++c) sbox[tid * 8 + c] = gt[o * 8 + c];
    sbox[tid * 8 + 7] = 0.0f;
}

__global__ __launch_bounds__(256) void sup_kernel(
        const float* __restrict__ sbox, u64* __restrict__ sup) {
    int i = blockIdx.y;
    int j = blockIdx.x * 256 + threadIdx.x;
    int word = j >> 6;
    int lane = threadIdx.x & 63;
    int wmaxj = (word << 6) + 63;
    if (wmaxj <= i) {
        if (lane == 0) sup[i * 16 + word] = 0ULL;
        return;
    }
    bool pred = false;
    if (j > i) {
        const float* A = &sbox[i * 8];
        const float* B = &sbox[j * 8];
        float inter = rect_inter_area(A[0], A[1], A[3], A[4], A[6],
                                      B[0], B[1], B[3], B[4], B[6]);
        float iou = inter / fmaxf(A[3] * A[4] + B[3] * B[4] - inter, 1e-8f);
        pred = iou > 0.1f;
    }
    u64 m = __ballot(pred);
    if (lane == 0) sup[i * 16 + word] = m;
}

__global__ __launch_bounds__(256) void iou3d_row_kernel(
        const float* __restrict__ pred, const float* __restrict__ gt,
        const int* __restrict__ sampled, u64* __restrict__ rowmax) {
    int i = blockIdx.y;
    int j = blockIdx.x * 256 + threadIdx.x;
    float Ax = pred[i * 7 + 0], Ay = pred[i * 7 + 1], Az = pred[i * 7 + 2];
    float Adx = pred[i * 7 + 3], Ady = pred[i * 7 + 4], Adz = pred[i * 7 + 5];
    float Ar = pred[i * 7 + 6];
    float msk = sampled[j] ? 1.0f : 0.0f;
    float Bx = gt[j * 8 + 0] * msk, By = gt[j * 8 + 1] * msk;
    float Bz = gt[j * 8 + 2] * msk;
    float Bdx = gt[j * 8 + 3] * msk, Bdy = gt[j * 8 + 4] * msk;
    float Bdz = gt[j * 8 + 5] * msk;
    float Br = gt[j * 8 + 6] * msk;
    float inter = rect_inter_area(Ax, Ay, Adx, Ady, Ar, Bx, By, Bdx, Bdy, Br);
    float amax = Az + Adz * 0.5f, amin = Az - Adz * 0.5f;
    float bmax = Bz + Bdz * 0.5f, bmin = Bz - Bdz * 0.5f;
    float oh = fmaxf(fminf(amax, bmax) - fmaxf(amin, bmin), 0.0f);
    float inter3d = inter * oh;
    float va = Adx * Ady * Adz, vb = Bdx * Bdy * Bdz;
    float iou = inter3d / fmaxf(va + vb - inter3d, 1e-8f);
    u64 pk = (((u64)__float_as_uint(iou)) << 32) | (u64)(1023 - j);
    atomicMax(&rowmax[i], pk);
}

__global__ __launch_bounds__(256) void fin_kernel(
        const u64* __restrict__ rowmax, float* __restrict__ out) {
    int i = blockIdx.x * 256 + threadIdx.x;
    u64 v = rowmax[i];
    float fv = __uint_as_float((unsigned int)(v >> 32));
    int j = 1023 - (int)(v & 0xFFFFFFFFULL);
    float mo = (fv > 0.75f) ? 1.0f : ((fv < 0.25f) ? 0.0f : fv);
    out[2 * NB + i] = mo;
    out[3 * NB + i] = (float)j;
}

// ---------------------------------------------------------------------------
// Workspace layout:
//   [0,       4096)    int   order[1024]
//   [4096,    36864)   float sbox[1024*8]
//   [36864,   40960)   int   sampled[1024]
//   [40960,   172032)  u64   sup[1024*16]
//   [172032,  188416)  float4 circ_s[1024]
//   [188416,  204800)  float4 circ_g[1024]
//   [204800,  221184)  float4 circ_p[1024]
//   [221184,  229376)  u64   rowmax[1024]   (fallback path only)
// ---------------------------------------------------------------------------
extern "C" void kernel_launch(void* const* d_in, const int* in_sizes, int n_in,
                              void* d_out, int out_size, void* d_ws, size_t ws_size,
                              hipStream_t stream) {
    const float* labels = (const float*)d_in[0];
    const float* pred   = (const float*)d_in[1];
    const float* gt     = (const float*)d_in[2];
    const float* cls    = (const float*)d_in[3];
    float* out = (float*)d_out;

    char* ws = (char*)d_ws;
    int* order   = (int*)ws;
    float* sbox  = (float*)(ws + 4096);
    int* sampled = (int*)(ws + 36864);
    u64* sup     = (u64*)(ws + 40960);
    float4* circ_s = (float4*)(ws + 172032);
    float4* circ_g = (float4*)(ws + 188416);
    float4* circ_p = (float4*)(ws + 204800);
    u64* rowmax  = (u64*)(ws + 221184);

    const size_t WS_NEEDED = 229376;

    if (ws_size >= WS_NEEDED) {
        prep3_kernel<<<16, 64, 0, stream>>>(labels, cls, gt, pred, out, order,
                                            sbox, circ_s, circ_g, circ_p, sup);
        fusedA_kernel<<<FB, 64, 0, stream>>>(sbox, circ_s, sup);
        nms_seq5_kernel<<<1, 64, 0, stream>>>(sup, order, sampled);
        fusedB_kernel<<<FB, 64, 0, stream>>>(pred, gt, sampled, circ_p,
                                             circ_g, out);
    } else {
        prep_kernel<<<1, 1024, 0, stream>>>(labels, cls, gt, out, order, sbox,
                                            rowmax);
        sup_kernel<<<dim3(4, 1024), 256, 0, stream>>>(sbox, sup);
        nms_seq5_kernel<<<1, 64, 0, stream>>>(sup, order, sampled);
        iou3d_row_kernel<<<dim3(4, 1024), 256, 0, stream>>>(pred, gt, sampled,
                                                            rowmax);
        fin_kernel<<<4, 256, 0, stream>>>(rowmax, out);
    }
}